// Round 3
// baseline (764.976 us; speedup 1.0000x reference)
//
#include <hip/hip_runtime.h>

// MaxUnpooling2D scatter-add — 16-channel / eighth-plane privatization.
// updates/mask: [32,64,64,128] f32/i32, out: [32,128,128,128] f32.
// out flat = (b<<21) | (bin<<7) | c  where bin = mask>>7 in [0,16384).
//
// R3: float4/int4 granules (4ch/block)            -> 190us
// R4: LDS 32KB for 4 blocks/CU -> VGPR cap spilled -> 600us (occupancy DID
//     double to 41%, so the mechanism was real but spill tripled traffic)
// R5: 512thr/8pos -> no spill, 16 waves/CU         -> 185us == R3!
//     Occupancy doubling changed NOTHING -> bottleneck is a shared,
//     already-saturated resource: per-request throughput. All accesses are
//     16B granules at 512B stride (64 lanes -> 64 distinct 64B sectors per
//     wave op; 32 separate 16B deposits per output line -> partial-sector
//     evictions, masked HBM bursts, WRITE 350MB vs 268 ideal).
// R6: widen to 16 channels/block. 4 adjacent lanes = (pos, quad 0..3) cover
//     one full 64B sector per load AND per store -> 4x fewer requests,
//     sector-complete writes (no masking), 8 partner blocks per output line.
//     LDS acc [2048 bins][16 ch] = 128 KiB DYNAMIC LDS (gfx950 allows
//     160KB/CU; 128KB/wg proven by the 8-phase GEMM template), 8 passes,
//     1024 thr, 1 block/CU = 16 waves/CU (R5 proved that's enough).
//
// XCD swizzle: b = bid&31 -> the 8 channel-group partners of a batch share
// bid%8 (same XCD); they jointly cover each 512B input/output line, so L2
// serves one fetch per line and merges 8x64B dirty sectors into full lines.
// 256 blocks = 1/CU exactly; 4 batches x 8 groups per XCD.

#define HWC (64 * 64 * 128)   // 2^19 input elements per batch
#define PBINS 2048            // bins per pass (16 output rows x 128 x)
#define NPASS 8

__global__ __launch_bounds__(1024, 4) void unpool_c16(
    const float* __restrict__ upd, const int* __restrict__ mask,
    float* __restrict__ out)
{
    extern __shared__ float acc[];     // [2048 bins][16 ch] = 128 KiB

    int bid = blockIdx.x;
    int b   = bid & 31;
    int c0  = (bid >> 5) << 4;         // 16-channel group base, 0..112

    int t    = threadIdx.x;
    int quad = t & 3;                  // which float4 within the 16 channels
    int prow = t >> 2;                 // 0..255

    const float* ubase = upd  + (size_t)b * HWC + c0 + quad * 4;
    const int*   mbase = mask + (size_t)b * HWC + c0 + quad * 4;
    float*       obase = out + ((size_t)b << 21) + c0;

    // Register-cache this block's full input: 16 iters, pos = prow + k*256.
    // Lanes 4i..4i+3 read 4 consecutive float4s = one 64B sector/request.
    // u: 64 VGPRs; packed bins: 32 VGPRs (bin < 16384 fits u16).
    float4 u[16];
    uint2  pk[16];
    #pragma unroll
    for (int k = 0; k < 16; ++k) {
        int pos = prow + (k << 8);     // (h,w) position 0..4095
        u[k] = *(const float4*)(ubase + (size_t)pos * 128);
        int4 m4 = *(const int4*)(mbase + (size_t)pos * 128);
        unsigned b0 = ((unsigned)m4.x) >> 7;
        unsigned b1 = ((unsigned)m4.y) >> 7;
        unsigned b2 = ((unsigned)m4.z) >> 7;
        unsigned b3 = ((unsigned)m4.w) >> 7;
        pk[k].x = b0 | (b1 << 16);
        pk[k].y = b2 | (b3 << 16);
    }

    float4* a4 = (float4*)acc;         // 8192 float4

    int cbase = quad << 2;             // this thread's channel offset 0/4/8/12

    for (int q = 0; q < NPASS; ++q) {
        // zero 128 KiB (8 float4 per thread, contiguous)
        #pragma unroll
        for (int k = 0; k < 8; ++k)
            a4[t + k * 1024] = make_float4(0.f, 0.f, 0.f, 0.f);
        __syncthreads();

        // scatter this pass's elements into LDS (ds_add, no return)
        unsigned uq = (unsigned)q;
        #pragma unroll
        for (int k = 0; k < 16; ++k) {
            unsigned b0 = pk[k].x & 0xffffu;
            unsigned b1 = pk[k].x >> 16;
            unsigned b2 = pk[k].y & 0xffffu;
            unsigned b3 = pk[k].y >> 16;
            if ((b0 >> 11) == uq) atomicAdd(&acc[((b0 & 2047u) << 4) + cbase + 0], u[k].x);
            if ((b1 >> 11) == uq) atomicAdd(&acc[((b1 & 2047u) << 4) + cbase + 1], u[k].y);
            if ((b2 >> 11) == uq) atomicAdd(&acc[((b2 & 2047u) << 4) + cbase + 2], u[k].z);
            if ((b3 >> 11) == uq) atomicAdd(&acc[((b3 & 2047u) << 4) + cbase + 3], u[k].w);
        }
        __syncthreads();

        // store the pass: lanes 4i..4i+3 cover one bin's 64B sector.
        // idx = bin*4 + quad'; out[b, q*2048+bin, c0 + quad'*4 .. +4]
        #pragma unroll
        for (int k = 0; k < 8; ++k) {
            int idx = t + k * 1024;
            int bin = idx >> 2;
            int qd  = idx & 3;
            *(float4*)(obase + (size_t)(q * PBINS + bin) * 128 + qd * 4) = a4[idx];
        }
        if (q < NPASS - 1) __syncthreads();   // next pass rewrites acc
    }
}

extern "C" void kernel_launch(void* const* d_in, const int* in_sizes, int n_in,
                              void* d_out, int out_size, void* d_ws, size_t ws_size,
                              hipStream_t stream) {
    const float* upd  = (const float*)d_in[0];
    const int*   mask = (const int*)d_in[1];
    float*       out  = (float*)d_out;

    // 128 KiB dynamic LDS needs the opt-in attribute (host-side, set once;
    // not a stream op -> graph-capture safe).
    static bool lds_ok = false;
    if (!lds_ok) {
        hipFuncSetAttribute((const void*)unpool_c16,
                            hipFuncAttributeMaxDynamicSharedMemorySize,
                            PBINS * 16 * 4);
        lds_ok = true;
    }

    // 32 batches x 8 channel-groups; every output element written exactly
    // once -> no memset, no global atomics.
    unpool_c16<<<256, 1024, PBINS * 16 * 4, stream>>>(upd, mask, out);
}